// Round 1
// baseline (1424.121 us; speedup 1.0000x reference)
//
#include <hip/hip_runtime.h>
#include <math.h>

#define SLOPE 0.2f

__device__ __forceinline__ float lrelu(float x) { return x > 0.f ? x : SLOPE * x; }

// ---------------------------------------------------------------------------
// h = x @ W   (CIN fixed at 128; COUT = 128 or 32)
// Block = 256 threads. Each thread owns one output channel j for 8 nodes.
// x tile staged in LDS; W rows read through L1/L2 (64 KB, heavily reused).
// ---------------------------------------------------------------------------
template <int COUT>
__global__ __launch_bounds__(256) void transform_kernel(
    const float* __restrict__ xin, const float* __restrict__ W,
    float* __restrict__ hout, int N)
{
    constexpr int GROUPS = 256 / COUT;   // 2 (COUT=128) or 8 (COUT=32)
    constexpr int NPT = 8;               // nodes per thread
    constexpr int NB = GROUPS * NPT;     // nodes per block: 16 or 64
    __shared__ __align__(16) float xs[NB][128];

    const int node0 = blockIdx.x * NB;
    const int total4 = NB * 128 / 4;
    const float4* src4 = (const float4*)(xin + (size_t)node0 * 128);
    float4* dst4 = (float4*)&xs[0][0];
    int lim4 = (N - node0) * 128 / 4;    // >= total4 unless tail block
    for (int i = threadIdx.x; i < total4; i += 256)
        dst4[i] = (i < lim4) ? src4[i] : make_float4(0.f, 0.f, 0.f, 0.f);
    __syncthreads();

    const int j = threadIdx.x % COUT;
    const int g = threadIdx.x / COUT;
    float acc[NPT];
#pragma unroll
    for (int m = 0; m < NPT; ++m) acc[m] = 0.f;

    for (int k = 0; k < 128; ++k) {
        float w = W[k * COUT + j];
#pragma unroll
        for (int m = 0; m < NPT; ++m) acc[m] += xs[g * NPT + m][k] * w;
    }
#pragma unroll
    for (int m = 0; m < NPT; ++m) {
        int n = node0 + g * NPT + m;
        if (n < N) hout[(size_t)n * COUT + j] = acc[m];
    }
}

// ---------------------------------------------------------------------------
// attention logits: al_src[n,h] = sum_c h[n,h,c]*a_src[h,c]  (same for dst)
// ---------------------------------------------------------------------------
template <int Hh, int Cc>
__global__ __launch_bounds__(256) void logits_kernel(
    const float* __restrict__ h, const float* __restrict__ a_src,
    const float* __restrict__ a_dst, float* __restrict__ alsrc,
    float* __restrict__ aldst, int N)
{
    int t = blockIdx.x * 256 + threadIdx.x;
    int n = t / Hh, hh = t % Hh;
    if (n >= N) return;
    const float* hp = h + (size_t)n * Hh * Cc + hh * Cc;
    const float* as = a_src + hh * Cc;
    const float* ad = a_dst + hh * Cc;
    float s = 0.f, d = 0.f;
#pragma unroll
    for (int c = 0; c < Cc; ++c) {
        float v = hp[c];
        s += v * as[c];
        d += v * ad[c];
    }
    alsrc[n * Hh + hh] = s;
    aldst[n * Hh + hh] = d;
}

// ---------------------------------------------------------------------------
// per-edge unnormalized softmax weight w = exp(leaky_relu(al_s + al_d));
// store w per edge, accumulate denom[dst] atomically. (No max-subtraction:
// logits are O(1) here, exp cannot overflow; denominator rescale is exact.)
// ---------------------------------------------------------------------------
template <int Hh>
__global__ __launch_bounds__(256) void edge_w_kernel(
    const int* __restrict__ src, const int* __restrict__ dst,
    const float* __restrict__ alsrc, const float* __restrict__ aldst,
    float* __restrict__ ew, float* __restrict__ denom, int E)
{
    int e = blockIdx.x * 256 + threadIdx.x;
    if (e >= E) return;
    int s = src[e], d = dst[e];
    float as[Hh], ad[Hh];
    if constexpr (Hh == 4) {
        float4 t1 = ((const float4*)alsrc)[s];
        as[0] = t1.x; as[1] = t1.y; as[2] = t1.z; as[3] = t1.w;
        float4 t2 = ((const float4*)aldst)[d];
        ad[0] = t2.x; ad[1] = t2.y; ad[2] = t2.z; ad[3] = t2.w;
    } else {
        as[0] = alsrc[s];
        ad[0] = aldst[d];
    }
    float wv[Hh];
#pragma unroll
    for (int hh = 0; hh < Hh; ++hh) {
        float x = lrelu(as[hh] + ad[hh]);
        float w = __expf(x);
        wv[hh] = w;
        unsafeAtomicAdd(&denom[d * Hh + hh], w);
    }
    if constexpr (Hh == 4)
        ((float4*)ew)[e] = make_float4(wv[0], wv[1], wv[2], wv[3]);
    else
        ew[e] = wv[0];
}

// ---------------------------------------------------------------------------
// scatter-add aggregation: acc[dst, c] += w_e * h[src, c]
// one thread per (edge, channel); HC consecutive threads share an edge
// ---------------------------------------------------------------------------
template <int Hh, int Cc>
__global__ __launch_bounds__(256) void edge_agg_kernel(
    const int* __restrict__ src, const int* __restrict__ dst,
    const float* __restrict__ ew, const float* __restrict__ h,
    float* __restrict__ acc, int E)
{
    constexpr int HC = Hh * Cc;
    int t = blockIdx.x * 256 + threadIdx.x;
    int e = t / HC;
    int c = t % HC;
    if (e >= E) return;
    int s = src[e], d = dst[e];
    float w = ew[(size_t)e * Hh + c / Cc];
    float val = w * h[(size_t)s * HC + c];
    unsafeAtomicAdd(&acc[(size_t)d * HC + c], val);
}

// ---------------------------------------------------------------------------
// epilogue: fold in self-loop contribution, divide by denom, +bias, (ELU)
// ---------------------------------------------------------------------------
template <int Hh, int Cc, bool DO_ELU>
__global__ __launch_bounds__(256) void epilogue_kernel(
    const float* __restrict__ h, const float* __restrict__ acc,
    const float* __restrict__ denom, const float* __restrict__ alsrc,
    const float* __restrict__ aldst, const float* __restrict__ bias,
    float* __restrict__ outf, int N)
{
    constexpr int HC = Hh * Cc;
    int t = blockIdx.x * 256 + threadIdx.x;
    int n = t / HC, c = t % HC;
    if (n >= N) return;
    int hh = c / Cc;
    float x = alsrc[n * Hh + hh] + aldst[n * Hh + hh];
    float wself = __expf(lrelu(x));
    float num = acc[(size_t)n * HC + c] + wself * h[(size_t)n * HC + c];
    float den = denom[n * Hh + hh] + wself + 1e-16f;
    float o = num / den + bias[c];
    if (DO_ELU) o = o > 0.f ? o : __expf(o) - 1.f;
    outf[(size_t)n * HC + c] = o;
}

// ---------------------------------------------------------------------------
// classification head: out[n,k] = h3[n,:] @ Wc[:,k] + bc[k]   (32 -> 2)
// ---------------------------------------------------------------------------
__global__ __launch_bounds__(256) void head_kernel(
    const float* __restrict__ h3, const float* __restrict__ Wc,
    const float* __restrict__ bc, float* __restrict__ out, int N)
{
    int t = blockIdx.x * 256 + threadIdx.x;
    int n = t / 2, k = t % 2;
    if (n >= N) return;
    float s = bc[k];
#pragma unroll
    for (int c = 0; c < 32; ++c) s += h3[(size_t)n * 32 + c] * Wc[c * 2 + k];
    out[(size_t)n * 2 + k] = s;
}

extern "C" void kernel_launch(void* const* d_in, const int* in_sizes, int n_in,
                              void* d_out, int out_size, void* d_ws, size_t ws_size,
                              hipStream_t stream)
{
    const float* x   = (const float*)d_in[0];
    const int*   ei  = (const int*)d_in[1];
    const float* W1  = (const float*)d_in[2];
    const float* a1s = (const float*)d_in[3];
    const float* a1d = (const float*)d_in[4];
    const float* b1  = (const float*)d_in[5];
    const float* W2  = (const float*)d_in[6];
    const float* a2s = (const float*)d_in[7];
    const float* a2d = (const float*)d_in[8];
    const float* b2  = (const float*)d_in[9];
    const float* W3  = (const float*)d_in[10];
    const float* a3s = (const float*)d_in[11];
    const float* a3d = (const float*)d_in[12];
    const float* b3  = (const float*)d_in[13];
    const float* Wc  = (const float*)d_in[14];
    const float* bc  = (const float*)d_in[15];

    const int N = in_sizes[0] / 128;
    const int E = in_sizes[1] / 2;
    const int* srcIdx = ei;
    const int* dstIdx = ei + E;

    float* ws    = (float*)d_ws;
    float* hbuf  = ws;                          // N*128
    float* acc   = hbuf  + (size_t)N * 128;     // N*128
    float* fbuf  = acc   + (size_t)N * 128;     // N*128
    float* alsrc = fbuf  + (size_t)N * 128;     // N*4
    float* aldst = alsrc + (size_t)N * 4;       // N*4
    float* denom = aldst + (size_t)N * 4;       // N*4
    float* ew    = denom + (size_t)N * 4;       // E*4

    float* node_out = (float*)d_out;            // N*2
    float* link_out = node_out + (size_t)N * 2; // N*32

    const int gridE   = (E + 255) / 256;

    // ---------------- layer 1 (IN=128 -> H=4,C=32, concat, ELU) ----------------
    hipMemsetAsync(acc, 0, (size_t)N * 128 * sizeof(float), stream);
    hipMemsetAsync(denom, 0, (size_t)N * 4 * sizeof(float), stream);
    transform_kernel<128><<<(N + 15) / 16, 256, 0, stream>>>(x, W1, hbuf, N);
    logits_kernel<4, 32><<<(N * 4 + 255) / 256, 256, 0, stream>>>(hbuf, a1s, a1d, alsrc, aldst, N);
    edge_w_kernel<4><<<gridE, 256, 0, stream>>>(srcIdx, dstIdx, alsrc, aldst, ew, denom, E);
    edge_agg_kernel<4, 32><<<(int)(((long long)E * 128 + 255) / 256), 256, 0, stream>>>(
        srcIdx, dstIdx, ew, hbuf, acc, E);
    epilogue_kernel<4, 32, true><<<(int)(((long long)N * 128 + 255) / 256), 256, 0, stream>>>(
        hbuf, acc, denom, alsrc, aldst, b1, fbuf, N);

    // ---------------- layer 2 (128 -> H=4,C=32, concat, ELU) ----------------
    hipMemsetAsync(acc, 0, (size_t)N * 128 * sizeof(float), stream);
    hipMemsetAsync(denom, 0, (size_t)N * 4 * sizeof(float), stream);
    transform_kernel<128><<<(N + 15) / 16, 256, 0, stream>>>(fbuf, W2, hbuf, N);
    logits_kernel<4, 32><<<(N * 4 + 255) / 256, 256, 0, stream>>>(hbuf, a2s, a2d, alsrc, aldst, N);
    edge_w_kernel<4><<<gridE, 256, 0, stream>>>(srcIdx, dstIdx, alsrc, aldst, ew, denom, E);
    edge_agg_kernel<4, 32><<<(int)(((long long)E * 128 + 255) / 256), 256, 0, stream>>>(
        srcIdx, dstIdx, ew, hbuf, acc, E);
    epilogue_kernel<4, 32, true><<<(int)(((long long)N * 128 + 255) / 256), 256, 0, stream>>>(
        hbuf, acc, denom, alsrc, aldst, b2, fbuf, N);

    // ---------------- layer 3 (128 -> H=1,C=32, no concat, no ELU) -------------
    hipMemsetAsync(acc, 0, (size_t)N * 32 * sizeof(float), stream);
    hipMemsetAsync(denom, 0, (size_t)N * 1 * sizeof(float), stream);
    transform_kernel<32><<<(N + 63) / 64, 256, 0, stream>>>(fbuf, W3, hbuf, N);
    logits_kernel<1, 32><<<(N + 255) / 256, 256, 0, stream>>>(hbuf, a3s, a3d, alsrc, aldst, N);
    edge_w_kernel<1><<<gridE, 256, 0, stream>>>(srcIdx, dstIdx, alsrc, aldst, ew, denom, E);
    edge_agg_kernel<1, 32><<<(int)(((long long)E * 32 + 255) / 256), 256, 0, stream>>>(
        srcIdx, dstIdx, ew, hbuf, acc, E);
    epilogue_kernel<1, 32, false><<<(int)(((long long)N * 32 + 255) / 256), 256, 0, stream>>>(
        hbuf, acc, denom, alsrc, aldst, b3, link_out, N);

    // ---------------- head: node_output = h3 @ Wc + bc -------------------------
    head_kernel<<<(N * 2 + 255) / 256, 256, 0, stream>>>(link_out, Wc, bc, node_out, N);
}

// Round 2
// 546.899 us; speedup vs baseline: 2.6040x; 2.6040x over previous
//
#include <hip/hip_runtime.h>
#include <math.h>

#define SLOPE 0.2f

__device__ __forceinline__ float lrelu(float x) { return x > 0.f ? x : SLOPE * x; }

// ---------------------------------------------------------------------------
// h = x @ W   (CIN fixed at 128; COUT = 128 or 32)
// ---------------------------------------------------------------------------
template <int COUT>
__global__ __launch_bounds__(256) void transform_kernel(
    const float* __restrict__ xin, const float* __restrict__ W,
    float* __restrict__ hout, int N)
{
    constexpr int GROUPS = 256 / COUT;   // 2 (COUT=128) or 8 (COUT=32)
    constexpr int NPT = 8;               // nodes per thread
    constexpr int NB = GROUPS * NPT;     // nodes per block: 16 or 64
    __shared__ __align__(16) float xs[NB][128];

    const int node0 = blockIdx.x * NB;
    const int total4 = NB * 128 / 4;
    const float4* src4 = (const float4*)(xin + (size_t)node0 * 128);
    float4* dst4 = (float4*)&xs[0][0];
    int lim4 = (N - node0) * 128 / 4;    // >= total4 unless tail block
    for (int i = threadIdx.x; i < total4; i += 256)
        dst4[i] = (i < lim4) ? src4[i] : make_float4(0.f, 0.f, 0.f, 0.f);
    __syncthreads();

    const int j = threadIdx.x % COUT;
    const int g = threadIdx.x / COUT;
    float acc[NPT];
#pragma unroll
    for (int m = 0; m < NPT; ++m) acc[m] = 0.f;

    for (int k = 0; k < 128; ++k) {
        float w = W[k * COUT + j];
#pragma unroll
        for (int m = 0; m < NPT; ++m) acc[m] += xs[g * NPT + m][k] * w;
    }
#pragma unroll
    for (int m = 0; m < NPT; ++m) {
        int n = node0 + g * NPT + m;
        if (n < N) hout[(size_t)n * COUT + j] = acc[m];
    }
}

// ---------------------------------------------------------------------------
// attention logits: al_src[n,h] = sum_c h[n,h,c]*a_src[h,c]  (same for dst)
// ---------------------------------------------------------------------------
template <int Hh, int Cc>
__global__ __launch_bounds__(256) void logits_kernel(
    const float* __restrict__ h, const float* __restrict__ a_src,
    const float* __restrict__ a_dst, float* __restrict__ alsrc,
    float* __restrict__ aldst, int N)
{
    int t = blockIdx.x * 256 + threadIdx.x;
    int n = t / Hh, hh = t % Hh;
    if (n >= N) return;
    const float* hp = h + (size_t)n * Hh * Cc + hh * Cc;
    const float* as = a_src + hh * Cc;
    const float* ad = a_dst + hh * Cc;
    float s = 0.f, d = 0.f;
#pragma unroll
    for (int c = 0; c < Cc; ++c) {
        float v = hp[c];
        s += v * as[c];
        d += v * ad[c];
    }
    alsrc[n * Hh + hh] = s;
    aldst[n * Hh + hh] = d;
}

// ---------------------------------------------------------------------------
// CSR build: count degrees, exclusive scan, scatter src indices by dst
// ---------------------------------------------------------------------------
__global__ __launch_bounds__(256) void count_kernel(
    const int* __restrict__ dst, int* __restrict__ deg, int E)
{
    int e = blockIdx.x * 256 + threadIdx.x;
    if (e < E) atomicAdd(&deg[dst[e]], 1);
}

__global__ __launch_bounds__(1024) void scan_kernel(
    const int* __restrict__ deg, int* __restrict__ offsets, int N)
{
    __shared__ int sdata[1024];
    const int tid = threadIdx.x;
    int carry = 0;
    for (int base = 0; base < N; base += 1024) {
        int i = base + tid;
        int v = (i < N) ? deg[i] : 0;
        __syncthreads();                 // protect sdata from prev-iter readers
        sdata[tid] = v;
        __syncthreads();
        for (int off = 1; off < 1024; off <<= 1) {
            int t = (tid >= off) ? sdata[tid - off] : 0;
            __syncthreads();
            sdata[tid] += t;
            __syncthreads();
        }
        int incl = sdata[tid];
        if (i < N) offsets[i] = carry + incl - v;   // exclusive
        carry += sdata[1023];            // stable: last write barrier above
    }
    if (tid == 0) offsets[N] = carry;
}

__global__ __launch_bounds__(256) void scatter_kernel(
    const int* __restrict__ src, const int* __restrict__ dst,
    int* __restrict__ cursor, int* __restrict__ src_sorted, int E)
{
    int e = blockIdx.x * 256 + threadIdx.x;
    if (e >= E) return;
    int pos = atomicAdd(&cursor[dst[e]], 1);
    src_sorted[pos] = src[e];
}

// ---------------------------------------------------------------------------
// Fused GAT aggregation (per-node gather, zero atomics):
//   for each node n: w_e = exp(lrelu(alsrc[src_e] + aldst[n])) for incoming
//   edges (staged via LDS in chunks), acc[c] = sum w_e * h[src_e, c],
//   denom = sum w_e; fold in self-loop analytically; divide, +bias, (ELU).
// HC threads per node, 256/HC nodes per block. Variable degree handled by
// looping all groups to the block-max chunk count (uniform barriers).
// ---------------------------------------------------------------------------
template <int Hh, int Cc, bool DO_ELU>
__global__ __launch_bounds__(256) void gat_agg_kernel(
    const int* __restrict__ offsets, const int* __restrict__ src_sorted,
    const float* __restrict__ h, const float* __restrict__ alsrc,
    const float* __restrict__ aldst, const float* __restrict__ bias,
    float* __restrict__ outf, int N)
{
    constexpr int HC = Hh * Cc;          // threads per node: 128 or 32
    constexpr int NPB = 256 / HC;        // nodes per block: 2 or 8
    constexpr int CHUNK = 64;            // edges staged per iteration
    __shared__ int   s_src[NPB][CHUNK];
    __shared__ float s_w[NPB][CHUNK][Hh];
    __shared__ int   s_nch[NPB];

    const int g  = threadIdx.x / HC;
    const int lt = threadIdx.x % HC;
    const int n  = blockIdx.x * NPB + g;
    const bool valid = n < N;

    int off0 = 0, deg = 0;
    if (valid) { off0 = offsets[n]; deg = offsets[n + 1] - off0; }
    if (lt == 0) s_nch[g] = (deg + CHUNK - 1) / CHUNK;
    __syncthreads();
    int maxch = 0;
#pragma unroll
    for (int i = 0; i < NPB; ++i) maxch = max(maxch, s_nch[i]);

    const int hh = lt / Cc;
    float adv[Hh];
    if (valid) {
        if constexpr (Hh == 4) {
            float4 t = ((const float4*)aldst)[n];
            adv[0] = t.x; adv[1] = t.y; adv[2] = t.z; adv[3] = t.w;
        } else {
            adv[0] = aldst[n];
        }
    }

    float accv = 0.f, den = 0.f;
    for (int ch = 0; ch < maxch; ++ch) {
        int base = ch * CHUNK;
        int cnt = deg - base;
        cnt = cnt < 0 ? 0 : (cnt > CHUNK ? CHUNK : cnt);
        __syncthreads();                 // LDS reuse fence
        for (int i = lt; i < cnt; i += HC) {
            int s = src_sorted[off0 + base + i];
            s_src[g][i] = s;
            if constexpr (Hh == 4) {
                float4 av = ((const float4*)alsrc)[s];
                s_w[g][i][0] = __expf(lrelu(av.x + adv[0]));
                s_w[g][i][1] = __expf(lrelu(av.y + adv[1]));
                s_w[g][i][2] = __expf(lrelu(av.z + adv[2]));
                s_w[g][i][3] = __expf(lrelu(av.w + adv[3]));
            } else {
                s_w[g][i][0] = __expf(lrelu(alsrc[s] + adv[0]));
            }
        }
        __syncthreads();
        for (int i = 0; i < cnt; ++i) {
            int s = s_src[g][i];
            float w = s_w[g][i][hh];
            accv += w * h[(size_t)s * HC + lt];
            den  += w;
        }
    }

    if (valid) {
        float wself = __expf(lrelu(alsrc[n * Hh + hh] + adv[hh]));
        accv += wself * h[(size_t)n * HC + lt];
        den  += wself + 1e-16f;
        float o = accv / den + bias[lt];
        if (DO_ELU) o = o > 0.f ? o : __expf(o) - 1.f;
        outf[(size_t)n * HC + lt] = o;
    }
}

// ---------------------------------------------------------------------------
// classification head: out[n,k] = h3[n,:] @ Wc[:,k] + bc[k]   (32 -> 2)
// ---------------------------------------------------------------------------
__global__ __launch_bounds__(256) void head_kernel(
    const float* __restrict__ h3, const float* __restrict__ Wc,
    const float* __restrict__ bc, float* __restrict__ out, int N)
{
    int t = blockIdx.x * 256 + threadIdx.x;
    int n = t / 2, k = t % 2;
    if (n >= N) return;
    float s = bc[k];
#pragma unroll
    for (int c = 0; c < 32; ++c) s += h3[(size_t)n * 32 + c] * Wc[c * 2 + k];
    out[(size_t)n * 2 + k] = s;
}

extern "C" void kernel_launch(void* const* d_in, const int* in_sizes, int n_in,
                              void* d_out, int out_size, void* d_ws, size_t ws_size,
                              hipStream_t stream)
{
    const float* x   = (const float*)d_in[0];
    const int*   ei  = (const int*)d_in[1];
    const float* W1  = (const float*)d_in[2];
    const float* a1s = (const float*)d_in[3];
    const float* a1d = (const float*)d_in[4];
    const float* b1  = (const float*)d_in[5];
    const float* W2  = (const float*)d_in[6];
    const float* a2s = (const float*)d_in[7];
    const float* a2d = (const float*)d_in[8];
    const float* b2  = (const float*)d_in[9];
    const float* W3  = (const float*)d_in[10];
    const float* a3s = (const float*)d_in[11];
    const float* a3d = (const float*)d_in[12];
    const float* b3  = (const float*)d_in[13];
    const float* Wc  = (const float*)d_in[14];
    const float* bc  = (const float*)d_in[15];

    const int N = in_sizes[0] / 128;
    const int E = in_sizes[1] / 2;
    const int* srcIdx = ei;
    const int* dstIdx = ei + E;

    float* ws    = (float*)d_ws;
    float* hbuf  = ws;                              // N*128
    float* fbuf  = hbuf + (size_t)N * 128;          // N*128
    float* alsrc = fbuf + (size_t)N * 128;          // N*4 (16B-aligned)
    float* aldst = alsrc + (size_t)N * 4;           // N*4
    int* deg        = (int*)(aldst + (size_t)N * 4); // N
    int* offsets    = deg + N;                       // N+1
    int* cursor     = offsets + N + 1;               // N
    int* src_sorted = cursor + N;                    // E

    float* node_out = (float*)d_out;                // N*2
    float* link_out = node_out + (size_t)N * 2;     // N*32

    const int gridE = (E + 255) / 256;

    // ---------------- CSR build (dst-sorted), reused by all 3 layers --------
    hipMemsetAsync(deg, 0, (size_t)N * sizeof(int), stream);
    count_kernel<<<gridE, 256, 0, stream>>>(dstIdx, deg, E);
    scan_kernel<<<1, 1024, 0, stream>>>(deg, offsets, N);
    hipMemcpyAsync(cursor, offsets, (size_t)N * sizeof(int),
                   hipMemcpyDeviceToDevice, stream);
    scatter_kernel<<<gridE, 256, 0, stream>>>(srcIdx, dstIdx, cursor, src_sorted, E);

    // ---------------- layer 1 (IN=128 -> H=4,C=32, concat, ELU) -------------
    transform_kernel<128><<<(N + 15) / 16, 256, 0, stream>>>(x, W1, hbuf, N);
    logits_kernel<4, 32><<<(N * 4 + 255) / 256, 256, 0, stream>>>(hbuf, a1s, a1d, alsrc, aldst, N);
    gat_agg_kernel<4, 32, true><<<(N + 1) / 2, 256, 0, stream>>>(
        offsets, src_sorted, hbuf, alsrc, aldst, b1, fbuf, N);

    // ---------------- layer 2 (128 -> H=4,C=32, concat, ELU) ----------------
    transform_kernel<128><<<(N + 15) / 16, 256, 0, stream>>>(fbuf, W2, hbuf, N);
    logits_kernel<4, 32><<<(N * 4 + 255) / 256, 256, 0, stream>>>(hbuf, a2s, a2d, alsrc, aldst, N);
    gat_agg_kernel<4, 32, true><<<(N + 1) / 2, 256, 0, stream>>>(
        offsets, src_sorted, hbuf, alsrc, aldst, b2, fbuf, N);

    // ---------------- layer 3 (128 -> H=1,C=32, no concat, no ELU) ----------
    transform_kernel<32><<<(N + 63) / 64, 256, 0, stream>>>(fbuf, W3, hbuf, N);
    logits_kernel<1, 32><<<(N + 255) / 256, 256, 0, stream>>>(hbuf, a3s, a3d, alsrc, aldst, N);
    gat_agg_kernel<1, 32, false><<<(N + 7) / 8, 256, 0, stream>>>(
        offsets, src_sorted, hbuf, alsrc, aldst, b3, link_out, N);

    // ---------------- head: node_output = h3 @ Wc + bc ----------------------
    head_kernel<<<(N * 2 + 255) / 256, 256, 0, stream>>>(link_out, Wc, bc, node_out, N);
}

// Round 3
// 484.624 us; speedup vs baseline: 2.9386x; 1.1285x over previous
//
#include <hip/hip_runtime.h>
#include <math.h>

#define SLOPE 0.2f

__device__ __forceinline__ float lrelu(float x) { return x > 0.f ? x : SLOPE * x; }

// ---------------------------------------------------------------------------
// h = x @ W   (CIN fixed at 128; COUT = 128 or 32)
// ---------------------------------------------------------------------------
template <int COUT>
__global__ __launch_bounds__(256) void transform_kernel(
    const float* __restrict__ xin, const float* __restrict__ W,
    float* __restrict__ hout, int N)
{
    constexpr int GROUPS = 256 / COUT;   // 2 (COUT=128) or 8 (COUT=32)
    constexpr int NPT = 8;               // nodes per thread
    constexpr int NB = GROUPS * NPT;     // nodes per block: 16 or 64
    __shared__ __align__(16) float xs[NB][128];

    const int node0 = blockIdx.x * NB;
    const int total4 = NB * 128 / 4;
    const float4* src4 = (const float4*)(xin + (size_t)node0 * 128);
    float4* dst4 = (float4*)&xs[0][0];
    int lim4 = (N - node0) * 128 / 4;    // >= total4 unless tail block
    for (int i = threadIdx.x; i < total4; i += 256)
        dst4[i] = (i < lim4) ? src4[i] : make_float4(0.f, 0.f, 0.f, 0.f);
    __syncthreads();

    const int j = threadIdx.x % COUT;
    const int g = threadIdx.x / COUT;
    float acc[NPT];
#pragma unroll
    for (int m = 0; m < NPT; ++m) acc[m] = 0.f;

    for (int k = 0; k < 128; ++k) {
        float w = W[k * COUT + j];
#pragma unroll
        for (int m = 0; m < NPT; ++m) acc[m] += xs[g * NPT + m][k] * w;
    }
#pragma unroll
    for (int m = 0; m < NPT; ++m) {
        int n = node0 + g * NPT + m;
        if (n < N) hout[(size_t)n * COUT + j] = acc[m];
    }
}

// ---------------------------------------------------------------------------
// attention logits: al_src[n,h] = sum_c h[n,h,c]*a_src[h,c]  (same for dst)
// ---------------------------------------------------------------------------
template <int Hh, int Cc>
__global__ __launch_bounds__(256) void logits_kernel(
    const float* __restrict__ h, const float* __restrict__ a_src,
    const float* __restrict__ a_dst, float* __restrict__ alsrc,
    float* __restrict__ aldst, int N)
{
    int t = blockIdx.x * 256 + threadIdx.x;
    int n = t / Hh, hh = t % Hh;
    if (n >= N) return;
    const float* hp = h + (size_t)n * Hh * Cc + hh * Cc;
    const float* as = a_src + hh * Cc;
    const float* ad = a_dst + hh * Cc;
    float s = 0.f, d = 0.f;
#pragma unroll
    for (int c = 0; c < Cc; ++c) {
        float v = hp[c];
        s += v * as[c];
        d += v * ad[c];
    }
    alsrc[n * Hh + hh] = s;
    aldst[n * Hh + hh] = d;
}

// ---------------------------------------------------------------------------
// CSR build: count degrees, 3-pass multi-block exclusive scan, scatter.
// Scan layout: 256 thr/block, 16 items/thr -> 4096 items/block.
// N=50000 -> 13 blocks; pass-2 single wave handles up to 64 blocks.
// ---------------------------------------------------------------------------
__global__ __launch_bounds__(256) void count_kernel(
    const int* __restrict__ dst, int* __restrict__ deg, int E)
{
    int e = blockIdx.x * 256 + threadIdx.x;
    if (e < E) atomicAdd(&deg[dst[e]], 1);
}

__global__ __launch_bounds__(256) void block_sum_kernel(
    const int* __restrict__ deg, int* __restrict__ blocksums, int N)
{
    int base = blockIdx.x * 4096 + threadIdx.x * 16;
    int s = 0;
#pragma unroll
    for (int i = 0; i < 16; ++i) {
        int idx = base + i;
        if (idx < N) s += deg[idx];
    }
#pragma unroll
    for (int off = 1; off < 64; off <<= 1) s += __shfl_xor(s, off);
    __shared__ int wsum[4];
    if ((threadIdx.x & 63) == 0) wsum[threadIdx.x >> 6] = s;
    __syncthreads();
    if (threadIdx.x == 0)
        blocksums[blockIdx.x] = wsum[0] + wsum[1] + wsum[2] + wsum[3];
}

// single wave scans <=64 block sums; writes exclusive bases + grand total
__global__ __launch_bounds__(64) void scan_sums_kernel(
    const int* __restrict__ blocksums, int* __restrict__ blockbase,
    int* __restrict__ total_out, int nb)
{
    int tid = threadIdx.x;
    int orig = (tid < nb) ? blocksums[tid] : 0;
    int v = orig;
#pragma unroll
    for (int off = 1; off < 64; off <<= 1) {
        int t = __shfl_up(v, off);
        if (tid >= off) v += t;
    }
    if (tid < nb) blockbase[tid] = v - orig;     // exclusive
    if (tid == nb - 1) *total_out = v;           // offsets[N]
}

__global__ __launch_bounds__(256) void scan_final_kernel(
    const int* __restrict__ deg, const int* __restrict__ blockbase,
    int* __restrict__ offsets, int N)
{
    int base = blockIdx.x * 4096 + threadIdx.x * 16;
    int v[16];
    int s = 0;
#pragma unroll
    for (int i = 0; i < 16; ++i) {
        int idx = base + i;
        v[i] = (idx < N) ? deg[idx] : 0;
        s += v[i];
    }
    int lane = threadIdx.x & 63, wid = threadIdx.x >> 6;
    int incl = s;
#pragma unroll
    for (int off = 1; off < 64; off <<= 1) {
        int t = __shfl_up(incl, off);
        if (lane >= off) incl += t;
    }
    __shared__ int wsum[4];
    if (lane == 63) wsum[wid] = incl;
    __syncthreads();
    int woff = 0;
    for (int i = 0; i < wid; ++i) woff += wsum[i];
    int run = blockbase[blockIdx.x] + woff + incl - s;  // thread-exclusive
#pragma unroll
    for (int i = 0; i < 16; ++i) {
        int idx = base + i;
        if (idx < N) offsets[idx] = run;
        run += v[i];
    }
}

__global__ __launch_bounds__(256) void scatter_kernel(
    const int* __restrict__ src, const int* __restrict__ dst,
    int* __restrict__ cursor, int* __restrict__ src_sorted, int E)
{
    int e = blockIdx.x * 256 + threadIdx.x;
    if (e >= E) return;
    int pos = atomicAdd(&cursor[dst[e]], 1);
    src_sorted[pos] = src[e];
}

// ---------------------------------------------------------------------------
// Fused GAT aggregation (per-node gather, zero atomics):
//   for each node n: w_e = exp(lrelu(alsrc[src_e] + aldst[n])) for incoming
//   edges (staged via LDS in chunks), acc[c] = sum w_e * h[src_e, c],
//   denom = sum w_e; fold in self-loop analytically; divide, +bias, (ELU).
// ---------------------------------------------------------------------------
template <int Hh, int Cc, bool DO_ELU>
__global__ __launch_bounds__(256) void gat_agg_kernel(
    const int* __restrict__ offsets, const int* __restrict__ src_sorted,
    const float* __restrict__ h, const float* __restrict__ alsrc,
    const float* __restrict__ aldst, const float* __restrict__ bias,
    float* __restrict__ outf, int N)
{
    constexpr int HC = Hh * Cc;          // threads per node: 128 or 32
    constexpr int NPB = 256 / HC;        // nodes per block: 2 or 8
    constexpr int CHUNK = 64;            // edges staged per iteration
    __shared__ int   s_src[NPB][CHUNK];
    __shared__ float s_w[NPB][CHUNK][Hh];
    __shared__ int   s_nch[NPB];

    const int g  = threadIdx.x / HC;
    const int lt = threadIdx.x % HC;
    const int n  = blockIdx.x * NPB + g;
    const bool valid = n < N;

    int off0 = 0, deg = 0;
    if (valid) { off0 = offsets[n]; deg = offsets[n + 1] - off0; }
    if (lt == 0) s_nch[g] = (deg + CHUNK - 1) / CHUNK;
    __syncthreads();
    int maxch = 0;
#pragma unroll
    for (int i = 0; i < NPB; ++i) maxch = max(maxch, s_nch[i]);

    const int hh = lt / Cc;
    float adv[Hh];
    if (valid) {
        if constexpr (Hh == 4) {
            float4 t = ((const float4*)aldst)[n];
            adv[0] = t.x; adv[1] = t.y; adv[2] = t.z; adv[3] = t.w;
        } else {
            adv[0] = aldst[n];
        }
    }

    float accv = 0.f, den = 0.f;
    for (int ch = 0; ch < maxch; ++ch) {
        int base = ch * CHUNK;
        int cnt = deg - base;
        cnt = cnt < 0 ? 0 : (cnt > CHUNK ? CHUNK : cnt);
        __syncthreads();                 // LDS reuse fence
        for (int i = lt; i < cnt; i += HC) {
            int s = src_sorted[off0 + base + i];
            s_src[g][i] = s;
            if constexpr (Hh == 4) {
                float4 av = ((const float4*)alsrc)[s];
                s_w[g][i][0] = __expf(lrelu(av.x + adv[0]));
                s_w[g][i][1] = __expf(lrelu(av.y + adv[1]));
                s_w[g][i][2] = __expf(lrelu(av.z + adv[2]));
                s_w[g][i][3] = __expf(lrelu(av.w + adv[3]));
            } else {
                s_w[g][i][0] = __expf(lrelu(alsrc[s] + adv[0]));
            }
        }
        __syncthreads();
        for (int i = 0; i < cnt; ++i) {
            int s = s_src[g][i];
            float w = s_w[g][i][hh];
            accv += w * h[(size_t)s * HC + lt];
            den  += w;
        }
    }

    if (valid) {
        float wself = __expf(lrelu(alsrc[n * Hh + hh] + adv[hh]));
        accv += wself * h[(size_t)n * HC + lt];
        den  += wself + 1e-16f;
        float o = accv / den + bias[lt];
        if (DO_ELU) o = o > 0.f ? o : __expf(o) - 1.f;
        outf[(size_t)n * HC + lt] = o;
    }
}

// ---------------------------------------------------------------------------
// classification head: out[n,k] = h3[n,:] @ Wc[:,k] + bc[k]   (32 -> 2)
// ---------------------------------------------------------------------------
__global__ __launch_bounds__(256) void head_kernel(
    const float* __restrict__ h3, const float* __restrict__ Wc,
    const float* __restrict__ bc, float* __restrict__ out, int N)
{
    int t = blockIdx.x * 256 + threadIdx.x;
    int n = t / 2, k = t % 2;
    if (n >= N) return;
    float s = bc[k];
#pragma unroll
    for (int c = 0; c < 32; ++c) s += h3[(size_t)n * 32 + c] * Wc[c * 2 + k];
    out[(size_t)n * 2 + k] = s;
}

extern "C" void kernel_launch(void* const* d_in, const int* in_sizes, int n_in,
                              void* d_out, int out_size, void* d_ws, size_t ws_size,
                              hipStream_t stream)
{
    const float* x   = (const float*)d_in[0];
    const int*   ei  = (const int*)d_in[1];
    const float* W1  = (const float*)d_in[2];
    const float* a1s = (const float*)d_in[3];
    const float* a1d = (const float*)d_in[4];
    const float* b1  = (const float*)d_in[5];
    const float* W2  = (const float*)d_in[6];
    const float* a2s = (const float*)d_in[7];
    const float* a2d = (const float*)d_in[8];
    const float* b2  = (const float*)d_in[9];
    const float* W3  = (const float*)d_in[10];
    const float* a3s = (const float*)d_in[11];
    const float* a3d = (const float*)d_in[12];
    const float* b3  = (const float*)d_in[13];
    const float* Wc  = (const float*)d_in[14];
    const float* bc  = (const float*)d_in[15];

    const int N = in_sizes[0] / 128;
    const int E = in_sizes[1] / 2;
    const int* srcIdx = ei;
    const int* dstIdx = ei + E;

    float* ws    = (float*)d_ws;
    float* hbuf  = ws;                              // N*128
    float* fbuf  = hbuf + (size_t)N * 128;          // N*128
    float* alsrc = fbuf + (size_t)N * 128;          // N*4 (16B-aligned)
    float* aldst = alsrc + (size_t)N * 4;           // N*4
    int* deg        = (int*)(aldst + (size_t)N * 4); // N
    int* offsets    = deg + N;                       // N+1
    int* cursor     = offsets + N + 1;               // N
    int* src_sorted = cursor + N;                    // E
    int* blocksums  = src_sorted + E;                // 64
    int* blockbase  = blocksums + 64;                // 64

    float* node_out = (float*)d_out;                // N*2
    float* link_out = node_out + (size_t)N * 2;     // N*32

    const int gridE = (E + 255) / 256;
    const int nb = (N + 4095) / 4096;               // scan blocks (13 <= 64)

    // ---------------- CSR build (dst-sorted), reused by all 3 layers --------
    hipMemsetAsync(deg, 0, (size_t)N * sizeof(int), stream);
    count_kernel<<<gridE, 256, 0, stream>>>(dstIdx, deg, E);
    block_sum_kernel<<<nb, 256, 0, stream>>>(deg, blocksums, N);
    scan_sums_kernel<<<1, 64, 0, stream>>>(blocksums, blockbase, offsets + N, nb);
    scan_final_kernel<<<nb, 256, 0, stream>>>(deg, blockbase, offsets, N);
    hipMemcpyAsync(cursor, offsets, (size_t)N * sizeof(int),
                   hipMemcpyDeviceToDevice, stream);
    scatter_kernel<<<gridE, 256, 0, stream>>>(srcIdx, dstIdx, cursor, src_sorted, E);

    // ---------------- layer 1 (IN=128 -> H=4,C=32, concat, ELU) -------------
    transform_kernel<128><<<(N + 15) / 16, 256, 0, stream>>>(x, W1, hbuf, N);
    logits_kernel<4, 32><<<(N * 4 + 255) / 256, 256, 0, stream>>>(hbuf, a1s, a1d, alsrc, aldst, N);
    gat_agg_kernel<4, 32, true><<<(N + 1) / 2, 256, 0, stream>>>(
        offsets, src_sorted, hbuf, alsrc, aldst, b1, fbuf, N);

    // ---------------- layer 2 (128 -> H=4,C=32, concat, ELU) ----------------
    transform_kernel<128><<<(N + 15) / 16, 256, 0, stream>>>(fbuf, W2, hbuf, N);
    logits_kernel<4, 32><<<(N * 4 + 255) / 256, 256, 0, stream>>>(hbuf, a2s, a2d, alsrc, aldst, N);
    gat_agg_kernel<4, 32, true><<<(N + 1) / 2, 256, 0, stream>>>(
        offsets, src_sorted, hbuf, alsrc, aldst, b2, fbuf, N);

    // ---------------- layer 3 (128 -> H=1,C=32, no concat, no ELU) ----------
    transform_kernel<32><<<(N + 63) / 64, 256, 0, stream>>>(fbuf, W3, hbuf, N);
    logits_kernel<1, 32><<<(N + 255) / 256, 256, 0, stream>>>(hbuf, a3s, a3d, alsrc, aldst, N);
    gat_agg_kernel<1, 32, false><<<(N + 7) / 8, 256, 0, stream>>>(
        offsets, src_sorted, hbuf, alsrc, aldst, b3, link_out, N);

    // ---------------- head: node_output = h3 @ Wc + bc ----------------------
    head_kernel<<<(N * 2 + 255) / 256, 256, 0, stream>>>(link_out, Wc, bc, node_out, N);
}

// Round 4
// 395.716 us; speedup vs baseline: 3.5988x; 1.2247x over previous
//
#include <hip/hip_runtime.h>
#include <math.h>

#define SLOPE 0.2f

__device__ __forceinline__ float lrelu(float x) { return x > 0.f ? x : SLOPE * x; }

// bf16 helpers (h is stored bf16 to halve gather traffic; error budget 1e-2)
__device__ __forceinline__ float bflo(unsigned int u) { return __uint_as_float(u << 16); }
__device__ __forceinline__ float bfhi(unsigned int u) { return __uint_as_float(u & 0xffff0000u); }
__device__ __forceinline__ unsigned short f2bf(float f) {   // round-nearest-even
    unsigned int u = __float_as_uint(f);
    unsigned int r = u + 0x7fffu + ((u >> 16) & 1u);
    return (unsigned short)(r >> 16);
}

// ---------------------------------------------------------------------------
// h = x @ W  (CIN=128), fused with attention logits:
//   al_src[n,hh] = sum_c h[n,hh,c]*a_src[hh,c]  (and a_dst) via shfl_xor
//   reduction over the 32 lanes of each head (head groups are 32-aligned
//   within the wave). h written as bf16.
// ---------------------------------------------------------------------------
template <int COUT, int Hh>
__global__ __launch_bounds__(256) void transform_kernel(
    const float* __restrict__ xin, const float* __restrict__ W,
    const float* __restrict__ a_src, const float* __restrict__ a_dst,
    unsigned short* __restrict__ hout, float* __restrict__ alsrc,
    float* __restrict__ aldst, int N)
{
    constexpr int GROUPS = 256 / COUT;   // 2 (COUT=128) or 8 (COUT=32)
    constexpr int NPT = 8;               // nodes per thread
    constexpr int NB = GROUPS * NPT;     // nodes per block: 16 or 64
    __shared__ __align__(16) float xs[NB][128];

    const int node0 = blockIdx.x * NB;
    const int total4 = NB * 128 / 4;
    const float4* src4 = (const float4*)(xin + (size_t)node0 * 128);
    float4* dst4 = (float4*)&xs[0][0];
    int lim4 = (N - node0) * 128 / 4;    // >= total4 unless tail block
    for (int i = threadIdx.x; i < total4; i += 256)
        dst4[i] = (i < lim4) ? src4[i] : make_float4(0.f, 0.f, 0.f, 0.f);
    __syncthreads();

    const int j = threadIdx.x % COUT;
    const int g = threadIdx.x / COUT;
    const int hh = j >> 5;               // head (Cc = 32)
    const int jl = j & 31;               // lane within head
    const float as = a_src[hh * 32 + jl];
    const float ad = a_dst[hh * 32 + jl];

    float acc[NPT];
#pragma unroll
    for (int m = 0; m < NPT; ++m) acc[m] = 0.f;

    for (int k = 0; k < 128; ++k) {
        float w = W[k * COUT + j];
#pragma unroll
        for (int m = 0; m < NPT; ++m) acc[m] += xs[g * NPT + m][k] * w;
    }

#pragma unroll
    for (int m = 0; m < NPT; ++m) {
        int n = node0 + g * NPT + m;
        float v = acc[m];
        float sv = v * as, dv = v * ad;
#pragma unroll
        for (int off = 16; off >= 1; off >>= 1) {
            sv += __shfl_xor(sv, off);
            dv += __shfl_xor(dv, off);
        }
        if (n < N) {
            hout[(size_t)n * COUT + j] = f2bf(v);
            if (jl == 0) {
                alsrc[n * Hh + hh] = sv;
                aldst[n * Hh + hh] = dv;
            }
        }
    }
}

// ---------------------------------------------------------------------------
// CSR build: count degrees, 3-pass multi-block exclusive scan, scatter.
// ---------------------------------------------------------------------------
__global__ __launch_bounds__(256) void count_kernel(
    const int* __restrict__ dst, int* __restrict__ deg, int E)
{
    int e = blockIdx.x * 256 + threadIdx.x;
    if (e < E) atomicAdd(&deg[dst[e]], 1);
}

__global__ __launch_bounds__(256) void block_sum_kernel(
    const int* __restrict__ deg, int* __restrict__ blocksums, int N)
{
    int base = blockIdx.x * 4096 + threadIdx.x * 16;
    int s = 0;
#pragma unroll
    for (int i = 0; i < 16; ++i) {
        int idx = base + i;
        if (idx < N) s += deg[idx];
    }
#pragma unroll
    for (int off = 1; off < 64; off <<= 1) s += __shfl_xor(s, off);
    __shared__ int wsum[4];
    if ((threadIdx.x & 63) == 0) wsum[threadIdx.x >> 6] = s;
    __syncthreads();
    if (threadIdx.x == 0)
        blocksums[blockIdx.x] = wsum[0] + wsum[1] + wsum[2] + wsum[3];
}

__global__ __launch_bounds__(64) void scan_sums_kernel(
    const int* __restrict__ blocksums, int* __restrict__ blockbase,
    int* __restrict__ total_out, int nb)
{
    int tid = threadIdx.x;
    int orig = (tid < nb) ? blocksums[tid] : 0;
    int v = orig;
#pragma unroll
    for (int off = 1; off < 64; off <<= 1) {
        int t = __shfl_up(v, off);
        if (tid >= off) v += t;
    }
    if (tid < nb) blockbase[tid] = v - orig;     // exclusive
    if (tid == nb - 1) *total_out = v;           // offsets[N]
}

__global__ __launch_bounds__(256) void scan_final_kernel(
    const int* __restrict__ deg, const int* __restrict__ blockbase,
    int* __restrict__ offsets, int* __restrict__ cursor, int N)
{
    int base = blockIdx.x * 4096 + threadIdx.x * 16;
    int v[16];
    int s = 0;
#pragma unroll
    for (int i = 0; i < 16; ++i) {
        int idx = base + i;
        v[i] = (idx < N) ? deg[idx] : 0;
        s += v[i];
    }
    int lane = threadIdx.x & 63, wid = threadIdx.x >> 6;
    int incl = s;
#pragma unroll
    for (int off = 1; off < 64; off <<= 1) {
        int t = __shfl_up(incl, off);
        if (lane >= off) incl += t;
    }
    __shared__ int wsum[4];
    if (lane == 63) wsum[wid] = incl;
    __syncthreads();
    int woff = 0;
    for (int i = 0; i < wid; ++i) woff += wsum[i];
    int run = blockbase[blockIdx.x] + woff + incl - s;  // thread-exclusive
#pragma unroll
    for (int i = 0; i < 16; ++i) {
        int idx = base + i;
        if (idx < N) { offsets[idx] = run; cursor[idx] = run; }
        run += v[i];
    }
}

__global__ __launch_bounds__(256) void scatter_kernel(
    const int* __restrict__ src, const int* __restrict__ dst,
    int* __restrict__ cursor, int* __restrict__ src_sorted, int E)
{
    int e = blockIdx.x * 256 + threadIdx.x;
    if (e >= E) return;
    int pos = atomicAdd(&cursor[dst[e]], 1);
    src_sorted[pos] = src[e];
}

// ---------------------------------------------------------------------------
// Fused GAT aggregation (per-node gather, zero atomics), bf16 h:
// 4 channels per thread (one 8B ushort4 load per edge), TPN = HC/4 threads
// per node. Edge weights staged in LDS per chunk; denominator in-register;
// self-loop folded analytically; divide, +bias, (ELU).
// ---------------------------------------------------------------------------
template <int Hh, int Cc, bool DO_ELU>
__global__ __launch_bounds__(256) void gat_agg_kernel(
    const int* __restrict__ offsets, const int* __restrict__ src_sorted,
    const unsigned short* __restrict__ h, const float* __restrict__ alsrc,
    const float* __restrict__ aldst, const float* __restrict__ bias,
    float* __restrict__ outf, int N)
{
    constexpr int HC  = Hh * Cc;         // 128 or 32
    constexpr int TPN = HC / 4;          // threads per node: 32 or 8
    constexpr int NPB = 256 / TPN;       // nodes per block: 8 or 32
    constexpr int CHUNK = 64;
    __shared__ int   s_src[NPB][CHUNK];
    __shared__ __align__(16) float s_w[NPB][CHUNK][Hh];
    __shared__ int   s_nch[NPB];

    const int g  = threadIdx.x / TPN;
    const int lt = threadIdx.x % TPN;
    const int n  = blockIdx.x * NPB + g;
    const bool valid = n < N;

    int off0 = 0, deg = 0;
    if (valid) { off0 = offsets[n]; deg = offsets[n + 1] - off0; }
    if (lt == 0) s_nch[g] = (deg + CHUNK - 1) / CHUNK;
    __syncthreads();
    int maxch = 0;
#pragma unroll
    for (int i = 0; i < NPB; ++i) maxch = max(maxch, s_nch[i]);

    const int hh = lt / (Cc / 4);        // head of this thread's 4 channels
    float adv[Hh];
    if (valid) {
        if constexpr (Hh == 4) {
            float4 t = ((const float4*)aldst)[n];
            adv[0] = t.x; adv[1] = t.y; adv[2] = t.z; adv[3] = t.w;
        } else {
            adv[0] = aldst[n];
        }
    }

    const uint2* h2 = (const uint2*)h;   // one row = TPN uint2 (8B = 4 ch)

    float a0 = 0.f, a1 = 0.f, a2 = 0.f, a3 = 0.f, den = 0.f;
    for (int ch = 0; ch < maxch; ++ch) {
        int base = ch * CHUNK;
        int cnt = deg - base;
        cnt = cnt < 0 ? 0 : (cnt > CHUNK ? CHUNK : cnt);
        __syncthreads();                 // LDS reuse fence
        for (int i = lt; i < cnt; i += TPN) {
            int s = src_sorted[off0 + base + i];
            s_src[g][i] = s;
            if constexpr (Hh == 4) {
                float4 av = ((const float4*)alsrc)[s];
                ((float4*)&s_w[g][i][0])[0] = make_float4(
                    __expf(lrelu(av.x + adv[0])), __expf(lrelu(av.y + adv[1])),
                    __expf(lrelu(av.z + adv[2])), __expf(lrelu(av.w + adv[3])));
            } else {
                s_w[g][i][0] = __expf(lrelu(alsrc[s] + adv[0]));
            }
        }
        __syncthreads();
        for (int i = 0; i < cnt; ++i) {
            int s = s_src[g][i];
            float w = s_w[g][i][hh];
            uint2 p = h2[(size_t)s * TPN + lt];
            a0 += w * bflo(p.x);
            a1 += w * bfhi(p.x);
            a2 += w * bflo(p.y);
            a3 += w * bfhi(p.y);
            den += w;
        }
    }

    if (valid) {
        float wself = __expf(lrelu(alsrc[n * Hh + hh] + adv[hh]));
        uint2 p = h2[(size_t)n * TPN + lt];
        a0 += wself * bflo(p.x);
        a1 += wself * bfhi(p.x);
        a2 += wself * bflo(p.y);
        a3 += wself * bfhi(p.y);
        den += wself + 1e-16f;
        float inv = 1.f / den;
        float4 bv = ((const float4*)bias)[lt];
        float4 o = make_float4(a0 * inv + bv.x, a1 * inv + bv.y,
                               a2 * inv + bv.z, a3 * inv + bv.w);
        if (DO_ELU) {
            o.x = o.x > 0.f ? o.x : __expf(o.x) - 1.f;
            o.y = o.y > 0.f ? o.y : __expf(o.y) - 1.f;
            o.z = o.z > 0.f ? o.z : __expf(o.z) - 1.f;
            o.w = o.w > 0.f ? o.w : __expf(o.w) - 1.f;
        }
        ((float4*)(outf + (size_t)n * HC))[lt] = o;
    }
}

// ---------------------------------------------------------------------------
// classification head: out[n,k] = h3[n,:] @ Wc[:,k] + bc[k]   (32 -> 2)
// ---------------------------------------------------------------------------
__global__ __launch_bounds__(256) void head_kernel(
    const float* __restrict__ h3, const float* __restrict__ Wc,
    const float* __restrict__ bc, float* __restrict__ out, int N)
{
    int t = blockIdx.x * 256 + threadIdx.x;
    int n = t / 2, k = t % 2;
    if (n >= N) return;
    float s = bc[k];
#pragma unroll
    for (int c = 0; c < 32; ++c) s += h3[(size_t)n * 32 + c] * Wc[c * 2 + k];
    out[(size_t)n * 2 + k] = s;
}

extern "C" void kernel_launch(void* const* d_in, const int* in_sizes, int n_in,
                              void* d_out, int out_size, void* d_ws, size_t ws_size,
                              hipStream_t stream)
{
    const float* x   = (const float*)d_in[0];
    const int*   ei  = (const int*)d_in[1];
    const float* W1  = (const float*)d_in[2];
    const float* a1s = (const float*)d_in[3];
    const float* a1d = (const float*)d_in[4];
    const float* b1  = (const float*)d_in[5];
    const float* W2  = (const float*)d_in[6];
    const float* a2s = (const float*)d_in[7];
    const float* a2d = (const float*)d_in[8];
    const float* b2  = (const float*)d_in[9];
    const float* W3  = (const float*)d_in[10];
    const float* a3s = (const float*)d_in[11];
    const float* a3d = (const float*)d_in[12];
    const float* b3  = (const float*)d_in[13];
    const float* Wc  = (const float*)d_in[14];
    const float* bc  = (const float*)d_in[15];

    const int N = in_sizes[0] / 128;
    const int E = in_sizes[1] / 2;
    const int* srcIdx = ei;
    const int* dstIdx = ei + E;

    float* ws    = (float*)d_ws;
    float* fbuf  = ws;                                  // N*128 fp32
    float* alsrc = fbuf + (size_t)N * 128;              // N*4 (16B aligned)
    float* aldst = alsrc + (size_t)N * 4;               // N*4
    unsigned short* hbuf = (unsigned short*)(aldst + (size_t)N * 4); // N*128 bf16
    int* deg        = (int*)(hbuf + (size_t)N * 128);   // N
    int* offsets    = deg + N;                          // N+1
    int* cursor     = offsets + N + 1;                  // N
    int* src_sorted = cursor + N;                       // E
    int* blocksums  = src_sorted + E;                   // 64
    int* blockbase  = blocksums + 64;                   // 64

    float* node_out = (float*)d_out;                    // N*2
    float* link_out = node_out + (size_t)N * 2;         // N*32

    const int gridE = (E + 255) / 256;
    const int nb = (N + 4095) / 4096;                   // scan blocks (<=64)

    // ---------------- CSR build (dst-sorted), reused by all 3 layers --------
    hipMemsetAsync(deg, 0, (size_t)N * sizeof(int), stream);
    count_kernel<<<gridE, 256, 0, stream>>>(dstIdx, deg, E);
    block_sum_kernel<<<nb, 256, 0, stream>>>(deg, blocksums, N);
    scan_sums_kernel<<<1, 64, 0, stream>>>(blocksums, blockbase, offsets + N, nb);
    scan_final_kernel<<<nb, 256, 0, stream>>>(deg, blockbase, offsets, cursor, N);
    scatter_kernel<<<gridE, 256, 0, stream>>>(srcIdx, dstIdx, cursor, src_sorted, E);

    // ---------------- layer 1 (IN=128 -> H=4,C=32, concat, ELU) -------------
    transform_kernel<128, 4><<<(N + 15) / 16, 256, 0, stream>>>(
        x, W1, a1s, a1d, hbuf, alsrc, aldst, N);
    gat_agg_kernel<4, 32, true><<<(N + 7) / 8, 256, 0, stream>>>(
        offsets, src_sorted, hbuf, alsrc, aldst, b1, fbuf, N);

    // ---------------- layer 2 (128 -> H=4,C=32, concat, ELU) ----------------
    transform_kernel<128, 4><<<(N + 15) / 16, 256, 0, stream>>>(
        fbuf, W2, a2s, a2d, hbuf, alsrc, aldst, N);
    gat_agg_kernel<4, 32, true><<<(N + 7) / 8, 256, 0, stream>>>(
        offsets, src_sorted, hbuf, alsrc, aldst, b2, fbuf, N);

    // ---------------- layer 3 (128 -> H=1,C=32, no concat, no ELU) ----------
    transform_kernel<32, 1><<<(N + 63) / 64, 256, 0, stream>>>(
        fbuf, W3, a3s, a3d, hbuf, alsrc, aldst, N);
    gat_agg_kernel<1, 32, false><<<(N + 31) / 32, 256, 0, stream>>>(
        offsets, src_sorted, hbuf, alsrc, aldst, b3, link_out, N);

    // ---------------- head: node_output = h3 @ Wc + bc ----------------------
    head_kernel<<<(N * 2 + 255) / 256, 256, 0, stream>>>(link_out, Wc, bc, node_out, N);
}